// Round 8
// baseline (504.482 us; speedup 1.0000x reference)
//
#include <hip/hip_runtime.h>
#include <hip/hip_bf16.h>

#define N_NODES_C 50000
#define N_EDGES_C 800000
#define IN_DIM_C 64
#define HID_C 256
#define EDGE_DIM_C 6
#define NEG_SLOPE_C 0.2f

typedef short short8 __attribute__((ext_vector_type(8)));
typedef float f32x4 __attribute__((ext_vector_type(4)));

static __device__ __forceinline__ float b2f(unsigned short u) {
    union { unsigned int i; float f; } x;
    x.i = ((unsigned int)u) << 16;
    return x.f;
}
static __device__ __forceinline__ unsigned short f2b(float f) {
    union { __hip_bfloat16 h; unsigned short u; } x;
    x.h = __float2bfloat16(f);
    return x.u;
}

// ---------------- fused: weight transposes (all blocks) + v = We@att_e (block 255) ----
__global__ void k_prep(const float* __restrict__ W1, const float* __restrict__ W2,
                       unsigned short* __restrict__ W1t, unsigned short* __restrict__ W2t,
                       const float* __restrict__ We1, const float* __restrict__ atte1,
                       const float* __restrict__ We2, const float* __restrict__ atte2,
                       float* __restrict__ v) {
    int tid = threadIdx.x;
    int i = blockIdx.x * blockDim.x + tid;
    if (i < IN_DIM_C * HID_C) {
        int k = i >> 8, n = i & 255;
        W1t[n * IN_DIM_C + k] = f2b(W1[i]);
    }
    if (i < HID_C * HID_C) {
        int k = i >> 8, n = i & 255;
        W2t[n * HID_C + k] = f2b(W2[i]);
    }
    if (blockIdx.x == 255) {
        __shared__ float red[256];
        for (int layer = 0; layer < 2; ++layer) {
            const float* We = layer ? We2 : We1;
            const float* ae = layer ? atte2 : atte1;
            for (int k = 0; k < EDGE_DIM_C; ++k) {
                red[tid] = We[k * HID_C + tid] * ae[tid];
                __syncthreads();
                for (int s = 128; s > 0; s >>= 1) {
                    if (tid < s) red[tid] += red[tid + s];
                    __syncthreads();
                }
                if (tid == 0) v[layer * 8 + k] = red[0];
                __syncthreads();
            }
        }
    }
}

// ---------------- edge-parallel: dst histogram + a_edge in ORIGINAL order (coalesced) ----
__global__ void k_pre(const int* __restrict__ dst, const float* __restrict__ eattr,
                      const float* __restrict__ v, int* __restrict__ deg,
                      float* __restrict__ ae1, float* __restrict__ ae2) {
    int e = blockIdx.x * blockDim.x + threadIdx.x;
    if (e >= N_EDGES_C) return;
    atomicAdd(&deg[dst[e]], 1);
    float a1 = 0.f, a2 = 0.f;
#pragma unroll
    for (int k = 0; k < EDGE_DIM_C; ++k) {
        float ea = eattr[e * EDGE_DIM_C + k];
        a1 += ea * v[k];
        a2 += ea * v[8 + k];
    }
    ae1[e] = a1;
    ae2[e] = a2;
}

// ---------------- two-level scan ----------------
__global__ void k_scan1(const int* __restrict__ deg, int* __restrict__ offs,
                        int* __restrict__ bsum) {
    __shared__ int tmp[256];
    int b = blockIdx.x, tid = threadIdx.x;
    int i = b * 256 + tid;
    int v = (i < N_NODES_C) ? deg[i] : 0;
    tmp[tid] = v;
    __syncthreads();
    for (int d = 1; d < 256; d <<= 1) {
        int t = (tid >= d) ? tmp[tid - d] : 0;
        __syncthreads();
        tmp[tid] += t;
        __syncthreads();
    }
    if (i < N_NODES_C) offs[i] = tmp[tid] - v;  // exclusive within block
    if (tid == 255) bsum[b] = tmp[255];
}
__global__ void k_scan2(const int* __restrict__ bsum, int* __restrict__ boff, int nb) {
    __shared__ int tmp[256];
    int tid = threadIdx.x;
    int v = (tid < nb) ? bsum[tid] : 0;
    tmp[tid] = v;
    __syncthreads();
    for (int d = 1; d < 256; d <<= 1) {
        int t = (tid >= d) ? tmp[tid - d] : 0;
        __syncthreads();
        tmp[tid] += t;
        __syncthreads();
    }
    if (tid < nb) boff[tid] = tmp[tid] - v;
}
__global__ void k_scan3(int* __restrict__ offs, const int* __restrict__ boff,
                        int* __restrict__ cur) {
    int b = blockIdx.x, tid = threadIdx.x;
    int i = b * 256 + tid;
    if (i < N_NODES_C) {
        int o = offs[i] + boff[b];
        offs[i] = o;
        cur[i] = o;
    }
    if (i == 0) offs[N_NODES_C] = N_EDGES_C;
}

// ---------------- perm build: single random 4B write per edge ----------------
__global__ void k_perm(const int* __restrict__ dst, int* __restrict__ cur,
                       int* __restrict__ perm) {
    int e = blockIdx.x * blockDim.x + threadIdx.x;
    if (e >= N_EDGES_C) return;
    int pos = atomicAdd(&cur[dst[e]], 1);
    perm[pos] = e;
}

// ---------------- CSR materialization: coalesced writes, random 4B reads (L2/L3) ------
__global__ void k_gather(const int* __restrict__ perm, const int* __restrict__ src,
                         const float* __restrict__ ae1, const float* __restrict__ ae2,
                         int* __restrict__ ssrc, float* __restrict__ sae1,
                         float* __restrict__ sae2) {
    int p = blockIdx.x * blockDim.x + threadIdx.x;
    if (p >= N_EDGES_C) return;
    int e = perm[p];
    ssrc[p] = src[e];
    sae1[p] = ae1[e];
    sae2[p] = ae2[e];
}

// ---------------- MFMA GEMM + fused per-row dots ----------------
template <int KT, bool SRCF32>
__global__ __launch_bounds__(256) void k_gemm_mfma(const void* __restrict__ Xv,
                                                   const unsigned short* __restrict__ Wt,
                                                   unsigned short* __restrict__ H,
                                                   const float* __restrict__ att_s,
                                                   const float* __restrict__ att_d,
                                                   float* __restrict__ asrc,
                                                   float* __restrict__ adst) {
    __shared__ unsigned short As[64 * 64];   // 8 KB
    __shared__ unsigned short Bs[256 * 64];  // 32 KB
    __shared__ float ds[4][64];
    __shared__ float dd[4][64];
    int tid = threadIdx.x;
    int w = tid >> 6, l = tid & 63;
    int lr = l & 15, lg = l >> 4;
    long mbase = (long)blockIdx.x * 64;

    float asv[4], adv[4];
#pragma unroll
    for (int ni = 0; ni < 4; ++ni) {
        int col = w * 64 + ni * 16 + lr;
        asv[ni] = att_s[col];
        adv[ni] = att_d[col];
    }

    f32x4 acc[4][4];
#pragma unroll
    for (int mi = 0; mi < 4; ++mi)
#pragma unroll
        for (int ni = 0; ni < 4; ++ni) acc[mi][ni] = (f32x4){0.f, 0.f, 0.f, 0.f};

    for (int k0 = 0; k0 < KT; k0 += 64) {
#pragma unroll
        for (int p = 0; p < 2; ++p) {
            int r = p * 32 + (tid >> 3);
            int c8 = tid & 7;
            long row = mbase + r;
            short8 val = {0, 0, 0, 0, 0, 0, 0, 0};
            if (row < N_NODES_C) {
                if (SRCF32) {
                    const float* Xf = (const float*)Xv;
                    const f32x4* p4 = (const f32x4*)&Xf[row * KT + k0 + c8 * 8];
                    f32x4 a0 = p4[0], a1 = p4[1];
#pragma unroll
                    for (int q = 0; q < 4; ++q) val[q] = (short)f2b(a0[q]);
#pragma unroll
                    for (int q = 0; q < 4; ++q) val[4 + q] = (short)f2b(a1[q]);
                } else {
                    const unsigned short* Xb = (const unsigned short*)Xv;
                    val = *(const short8*)&Xb[row * KT + k0 + c8 * 8];
                }
            }
            *(short8*)&As[r * 64 + ((c8 ^ (r & 7)) * 8)] = val;
        }
        {
            int n = tid;
#pragma unroll
            for (int c8 = 0; c8 < 8; ++c8) {
                *(short8*)&Bs[n * 64 + ((c8 ^ (n & 7)) * 8)] =
                    *(const short8*)&Wt[(long)n * KT + k0 + c8 * 8];
            }
        }
        __syncthreads();
#pragma unroll
        for (int kk = 0; kk < 2; ++kk) {
            int cblk = kk * 4 + lg;
            short8 a[4], b[4];
#pragma unroll
            for (int mi = 0; mi < 4; ++mi) {
                int R = mi * 16 + lr;
                a[mi] = *(const short8*)&As[R * 64 + ((cblk ^ (R & 7)) * 8)];
            }
#pragma unroll
            for (int ni = 0; ni < 4; ++ni) {
                int Nr = w * 64 + ni * 16 + lr;
                b[ni] = *(const short8*)&Bs[Nr * 64 + ((cblk ^ (Nr & 7)) * 8)];
            }
#pragma unroll
            for (int mi = 0; mi < 4; ++mi)
#pragma unroll
                for (int ni = 0; ni < 4; ++ni)
                    acc[mi][ni] = __builtin_amdgcn_mfma_f32_16x16x32_bf16(a[mi], b[ni],
                                                                          acc[mi][ni], 0, 0, 0);
        }
        __syncthreads();
    }

#pragma unroll
    for (int mi = 0; mi < 4; ++mi) {
#pragma unroll
        for (int r = 0; r < 4; ++r) {
            int rowl = mi * 16 + lg * 4 + r;
            long row = mbase + rowl;
            float ps = 0.f, pd = 0.f;
#pragma unroll
            for (int ni = 0; ni < 4; ++ni) {
                float h = acc[mi][ni][r];
                ps += h * asv[ni];
                pd += h * adv[ni];
            }
#pragma unroll
            for (int o = 1; o < 16; o <<= 1) {
                ps += __shfl_xor(ps, o, 16);
                pd += __shfl_xor(pd, o, 16);
            }
            if (lr == 0) {
                ds[w][rowl] = ps;
                dd[w][rowl] = pd;
            }
            if (row < N_NODES_C) {
#pragma unroll
                for (int ni = 0; ni < 4; ++ni) {
                    H[row * HID_C + w * 64 + ni * 16 + lr] = f2b(acc[mi][ni][r]);
                }
            }
        }
    }
    __syncthreads();
    if (tid < 64) {
        long row = mbase + tid;
        if (row < N_NODES_C) {
            asrc[row] = ds[0][tid] + ds[1][tid] + ds[2][tid] + ds[3][tid];
            adst[row] = dd[0][tid] + dd[1][tid] + dd[2][tid] + dd[3][tid];
        }
    }
}

// ---------------- halfwave-per-node: softmax denom + packed normalized weights ----------
// enc[p] = (src << 16) | bf16(w/denom)   (src < 50000 < 2^16)
__global__ __launch_bounds__(256) void k_norm(const int* __restrict__ offs,
                                              const int* __restrict__ ssrc,
                                              const float* __restrict__ sae,
                                              const float* __restrict__ asrc,
                                              const float* __restrict__ adst,
                                              float* __restrict__ wts,
                                              unsigned int* __restrict__ enc) {
    int tid = threadIdx.x;
    int hw = tid >> 5, l = tid & 31;
    int node = blockIdx.x * 8 + hw;
    int off0 = offs[node];
    int deg = offs[node + 1] - off0;
    float adi = adst[node];
    float s = 0.f;
    for (int j = l; j < deg; j += 32) {
        int si = ssrc[off0 + j];
        float a = asrc[si] + adi + sae[off0 + j];
        a = (a > 0.f) ? a : NEG_SLOPE_C * a;
        float w = __expf(a);
        wts[off0 + j] = w;
        s += w;
    }
#pragma unroll
    for (int o = 16; o > 0; o >>= 1) s += __shfl_xor(s, o, 32);
    float inv = 1.0f / (s + 1e-16f);
    for (int j = l; j < deg; j += 32) {
        unsigned int sv = ((unsigned int)ssrc[off0 + j]) << 16;
        enc[off0 + j] = sv | (unsigned int)f2b(wts[off0 + j] * inv);
    }
}

// ---------------- XCD-sliced aggregation: slice = blockIdx & 7 -> 32 columns ----------
// Per-XCD H footprint = 3.2 MB (fits 4 MB L2). 16 lanes per node, 2 cols/lane.
__global__ __launch_bounds__(256) void k_aggrslice(const int* __restrict__ offs,
                                                   const unsigned int* __restrict__ enc,
                                                   const unsigned short* __restrict__ H,
                                                   const float* __restrict__ bias,
                                                   void* __restrict__ outp, int mode) {
    int tid = threadIdx.x;
    int slice = blockIdx.x & 7;
    int grp = blockIdx.x >> 3;
    int g = tid >> 4;          // node subgroup 0..15
    int l = tid & 15;
    int node = grp * 16 + g;
    int off0 = offs[node];
    int deg = offs[node + 1] - off0;
    int ce = slice * 32 + l * 2;   // element column (2 cols per lane)
    const unsigned int* ep = enc + off0;

    float a0 = 0.f, a1 = 0.f;
    int j = 0;
    for (; j + 3 < deg; j += 4) {
        unsigned int e0 = __builtin_nontemporal_load(ep + j);
        unsigned int e1 = __builtin_nontemporal_load(ep + j + 1);
        unsigned int e2 = __builtin_nontemporal_load(ep + j + 2);
        unsigned int e3 = __builtin_nontemporal_load(ep + j + 3);
        ushort2 h0 = *(const ushort2*)&H[(e0 >> 16) * HID_C + ce];
        ushort2 h1 = *(const ushort2*)&H[(e1 >> 16) * HID_C + ce];
        ushort2 h2 = *(const ushort2*)&H[(e2 >> 16) * HID_C + ce];
        ushort2 h3 = *(const ushort2*)&H[(e3 >> 16) * HID_C + ce];
        float w0 = b2f((unsigned short)(e0 & 0xffffu));
        float w1 = b2f((unsigned short)(e1 & 0xffffu));
        float w2 = b2f((unsigned short)(e2 & 0xffffu));
        float w3 = b2f((unsigned short)(e3 & 0xffffu));
        a0 += w0 * b2f(h0.x) + w1 * b2f(h1.x) + w2 * b2f(h2.x) + w3 * b2f(h3.x);
        a1 += w0 * b2f(h0.y) + w1 * b2f(h1.y) + w2 * b2f(h2.y) + w3 * b2f(h3.y);
    }
    for (; j < deg; ++j) {
        unsigned int e0 = __builtin_nontemporal_load(ep + j);
        ushort2 h0 = *(const ushort2*)&H[(e0 >> 16) * HID_C + ce];
        float w0 = b2f((unsigned short)(e0 & 0xffffu));
        a0 += w0 * b2f(h0.x);
        a1 += w0 * b2f(h0.y);
    }

    float r0 = a0 + bias[ce];
    float r1 = a1 + bias[ce + 1];
    if (mode == 1) {
        ushort2 r;
        r.x = f2b(fmaxf(r0, 0.f));
        r.y = f2b(fmaxf(r1, 0.f));
        *(ushort2*)&((unsigned short*)outp)[(long)node * HID_C + ce] = r;
    } else {
        float2 r;
        r.x = r0;
        r.y = r1;
        *(float2*)&((float*)outp)[(long)node * HID_C + ce] = r;
    }
}

extern "C" void kernel_launch(void* const* d_in, const int* in_sizes, int n_in,
                              void* d_out, int out_size, void* d_ws, size_t ws_size,
                              hipStream_t stream) {
    const float* x     = (const float*)d_in[0];
    const int*   ei    = (const int*)d_in[1];     // [2, E]: row0=src, row1=dst
    const float* eattr = (const float*)d_in[2];
    const float* W1    = (const float*)d_in[3];
    const float* atts1 = (const float*)d_in[4];
    const float* attd1 = (const float*)d_in[5];
    const float* We1   = (const float*)d_in[6];
    const float* atte1 = (const float*)d_in[7];
    const float* b1    = (const float*)d_in[8];
    const float* W2    = (const float*)d_in[9];
    const float* atts2 = (const float*)d_in[10];
    const float* attd2 = (const float*)d_in[11];
    const float* We2   = (const float*)d_in[12];
    const float* atte2 = (const float*)d_in[13];
    const float* b2    = (const float*)d_in[14];
    float* out = (float*)d_out;

    char* ws = (char*)d_ws;
    size_t off = 0;
    auto alloc = [&](size_t bytes) -> void* {
        void* p = ws + off;
        off = (off + bytes + 255) & ~(size_t)255;
        return p;
    };
    int*   deg  = (int*)alloc((size_t)N_NODES_C * 4);
    int*   offs = (int*)alloc(((size_t)N_NODES_C + 1) * 4);
    int*   cur  = (int*)alloc((size_t)N_NODES_C * 4);
    int*   perm = (int*)alloc((size_t)N_EDGES_C * 4);
    int*   ssrc = (int*)alloc((size_t)N_EDGES_C * 4);
    float* ae1  = (float*)alloc((size_t)N_EDGES_C * 4);
    float* ae2  = (float*)alloc((size_t)N_EDGES_C * 4);
    float* sae1 = (float*)alloc((size_t)N_EDGES_C * 4);
    float* sae2 = (float*)alloc((size_t)N_EDGES_C * 4);
    float* asrc = (float*)alloc((size_t)N_NODES_C * 4);
    float* adst = (float*)alloc((size_t)N_NODES_C * 4);
    float* v    = (float*)alloc(64);
    int*   bsum = (int*)alloc(256 * 4);
    int*   boff = (int*)alloc(257 * 4);
    unsigned short* W1t = (unsigned short*)alloc((size_t)HID_C * IN_DIM_C * 2);
    unsigned short* W2t = (unsigned short*)alloc((size_t)HID_C * HID_C * 2);
    unsigned short* h1  = (unsigned short*)alloc((size_t)N_NODES_C * HID_C * 2);  // also h2
    unsigned short* g1  = (unsigned short*)alloc((size_t)N_NODES_C * HID_C * 2);

    // wts/enc reuse ae1/ae2 (dead after k_gather)
    float*        wts = ae1;
    unsigned int* enc = (unsigned int*)ae2;

    const int* src = ei;
    const int* dst = ei + N_EDGES_C;
    int nb = (N_NODES_C + 255) / 256;  // 196

    hipMemsetAsync(deg, 0, (size_t)N_NODES_C * 4, stream);

    k_prep<<<256, 256, 0, stream>>>(W1, W2, W1t, W2t, We1, atte1, We2, atte2, v);
    k_pre<<<(N_EDGES_C + 255) / 256, 256, 0, stream>>>(dst, eattr, v, deg, ae1, ae2);
    k_scan1<<<nb, 256, 0, stream>>>(deg, offs, bsum);
    k_scan2<<<1, 256, 0, stream>>>(bsum, boff, nb);
    k_scan3<<<nb, 256, 0, stream>>>(offs, boff, cur);
    k_perm<<<(N_EDGES_C + 255) / 256, 256, 0, stream>>>(dst, cur, perm);
    k_gather<<<(N_EDGES_C + 255) / 256, 256, 0, stream>>>(perm, src, ae1, ae2,
                                                          ssrc, sae1, sae2);

    int gemm_grid = (N_NODES_C + 63) / 64;
    int aggr_grid = (N_NODES_C / 16) * 8;   // 25000 blocks, slice = blockIdx & 7
    // layer 1
    k_gemm_mfma<IN_DIM_C, true><<<gemm_grid, 256, 0, stream>>>(x, W1t, h1, atts1, attd1,
                                                               asrc, adst);
    k_norm<<<N_NODES_C / 8, 256, 0, stream>>>(offs, ssrc, sae1, asrc, adst, wts, enc);
    k_aggrslice<<<aggr_grid, 256, 0, stream>>>(offs, enc, h1, b1, g1, 1);
    // layer 2 (h2 aliases h1 buffer)
    k_gemm_mfma<HID_C, false><<<gemm_grid, 256, 0, stream>>>(g1, W2t, h1, atts2, attd2,
                                                             asrc, adst);
    k_norm<<<N_NODES_C / 8, 256, 0, stream>>>(offs, ssrc, sae2, asrc, adst, wts, enc);
    k_aggrslice<<<aggr_grid, 256, 0, stream>>>(offs, enc, h1, b2, out, 0);
}

// Round 9
// 302.141 us; speedup vs baseline: 1.6697x; 1.6697x over previous
//
#include <hip/hip_runtime.h>
#include <hip/hip_bf16.h>

#define N_NODES_C 50000
#define N_EDGES_C 800000
#define IN_DIM_C 64
#define HID_C 256
#define EDGE_DIM_C 6
#define NEG_SLOPE_C 0.2f

typedef short short8 __attribute__((ext_vector_type(8)));
typedef float f32x4 __attribute__((ext_vector_type(4)));

static __device__ __forceinline__ float b2f(unsigned short u) {
    union { unsigned int i; float f; } x;
    x.i = ((unsigned int)u) << 16;
    return x.f;
}
static __device__ __forceinline__ unsigned short f2b(float f) {
    union { __hip_bfloat16 h; unsigned short u; } x;
    x.h = __float2bfloat16(f);
    return x.u;
}

// ---- shared aggregation core: one halfwave aggregates one node's 8 columns/lane ----
// Lane l caches (src,w) for edges l and l+32 in registers; shfl-broadcast in the
// gather loop; 8 rows in flight. acc[8] = unnormalized sum, returns 1/denom.
static __device__ __forceinline__ float aggr_node(int off0, int deg, float adi,
                                                  const int* __restrict__ ssrc,
                                                  const float* __restrict__ sae,
                                                  const float* __restrict__ asrc,
                                                  const unsigned short* __restrict__ H,
                                                  int l, float* acc) {
    int sidx0 = 0, sidx1 = 0;
    float w0 = 0.f, w1 = 0.f;
    if (l < deg) {
        sidx0 = ssrc[off0 + l];
        float a = asrc[sidx0] + adi + sae[off0 + l];
        a = (a > 0.f) ? a : NEG_SLOPE_C * a;
        w0 = __expf(a);
    }
    if (32 + l < deg) {
        sidx1 = ssrc[off0 + 32 + l];
        float a = asrc[sidx1] + adi + sae[off0 + 32 + l];
        a = (a > 0.f) ? a : NEG_SLOPE_C * a;
        w1 = __expf(a);
    }
    float s = w0 + w1;
    for (int j = 64 + l; j < deg; j += 32) {  // cold tail
        int si = ssrc[off0 + j];
        float a = asrc[si] + adi + sae[off0 + j];
        a = (a > 0.f) ? a : NEG_SLOPE_C * a;
        s += __expf(a);
    }
#pragma unroll
    for (int o = 16; o > 0; o >>= 1) s += __shfl_xor(s, o, 32);
    float inv = 1.0f / (s + 1e-16f);

    int c8 = l * 8;
#pragma unroll
    for (int q = 0; q < 8; ++q) acc[q] = 0.f;

    auto fetch = [&](int j, int& si, float& wv) {
        if (j < 32) {
            si = __shfl(sidx0, j, 32);
            wv = __shfl(w0, j, 32);
        } else if (j < 64) {
            si = __shfl(sidx1, j - 32, 32);
            wv = __shfl(w1, j - 32, 32);
        } else {
            si = ssrc[off0 + j];
            float a = asrc[si] + adi + sae[off0 + j];
            a = (a > 0.f) ? a : NEG_SLOPE_C * a;
            wv = __expf(a);
        }
    };

    int j = 0;
    for (; j + 7 < deg; j += 8) {
        int ii[8];
        float uu[8];
#pragma unroll
        for (int q = 0; q < 8; ++q) fetch(j + q, ii[q], uu[q]);
        short8 h[8];
#pragma unroll
        for (int q = 0; q < 8; ++q) h[q] = *(const short8*)&H[(long)ii[q] * HID_C + c8];
#pragma unroll
        for (int t = 0; t < 8; ++t)
#pragma unroll
            for (int q = 0; q < 8; ++q) acc[q] += uu[t] * b2f((unsigned short)h[t][q]);
    }
    for (; j + 3 < deg; j += 4) {
        int ii[4];
        float uu[4];
#pragma unroll
        for (int q = 0; q < 4; ++q) fetch(j + q, ii[q], uu[q]);
        short8 h[4];
#pragma unroll
        for (int q = 0; q < 4; ++q) h[q] = *(const short8*)&H[(long)ii[q] * HID_C + c8];
#pragma unroll
        for (int t = 0; t < 4; ++t)
#pragma unroll
            for (int q = 0; q < 8; ++q) acc[q] += uu[t] * b2f((unsigned short)h[t][q]);
    }
    for (; j < deg; ++j) {
        int i0;
        float u0;
        fetch(j, i0, u0);
        short8 h0 = *(const short8*)&H[(long)i0 * HID_C + c8];
#pragma unroll
        for (int q = 0; q < 8; ++q) acc[q] += u0 * b2f((unsigned short)h0[q]);
    }
    return inv;
}

// ---------------- prep: W transposes + v12 (block 255) + zero deg ----------------
__global__ void k_prep(const float* __restrict__ W1, const float* __restrict__ W2,
                       unsigned short* __restrict__ W1t, unsigned short* __restrict__ W2t,
                       const float* __restrict__ We1, const float* __restrict__ atte1,
                       const float* __restrict__ We2, const float* __restrict__ atte2,
                       float* __restrict__ v, int* __restrict__ deg) {
    int tid = threadIdx.x;
    int i = blockIdx.x * blockDim.x + tid;
    if (i < N_NODES_C) deg[i] = 0;
    if (i < IN_DIM_C * HID_C) {
        int k = i >> 8, n = i & 255;
        W1t[n * IN_DIM_C + k] = f2b(W1[i]);
    }
    if (i < HID_C * HID_C) {
        int k = i >> 8, n = i & 255;
        W2t[n * HID_C + k] = f2b(W2[i]);
    }
    if (blockIdx.x == 255) {
        __shared__ float red[256];
        for (int layer = 0; layer < 2; ++layer) {
            const float* We = layer ? We2 : We1;
            const float* ae = layer ? atte2 : atte1;
            for (int k = 0; k < EDGE_DIM_C; ++k) {
                red[tid] = We[k * HID_C + tid] * ae[tid];
                __syncthreads();
                for (int s = 128; s > 0; s >>= 1) {
                    if (tid < s) red[tid] += red[tid + s];
                    __syncthreads();
                }
                if (tid == 0) v[layer * 8 + k] = red[0];
                __syncthreads();
            }
        }
    }
}

#define GEMM1_BLOCKS 782  // ceil(50000/64)

// ---------------- fused: GEMM1 (blocks < 782) + edge-pre (blocks >= 782) ----------
__global__ __launch_bounds__(256) void k_pre_gemm1(
    const float* __restrict__ X, const unsigned short* __restrict__ Wt,
    unsigned short* __restrict__ H, const float* __restrict__ att_s,
    const float* __restrict__ att_d, float* __restrict__ asrc,
    float* __restrict__ adst,
    const int* __restrict__ dst, const float* __restrict__ eattr,
    const float* __restrict__ v, int* __restrict__ deg,
    float* __restrict__ ae1, float* __restrict__ ae2) {
    __shared__ unsigned short As[64 * 64];
    __shared__ unsigned short Bs[256 * 64];
    __shared__ float ds[4][64];
    __shared__ float dd[4][64];
    int tid = threadIdx.x;

    if (blockIdx.x >= GEMM1_BLOCKS) {
        // ---- edge-pre: histogram + a_edge (original order, coalesced) ----
        int e = (blockIdx.x - GEMM1_BLOCKS) * 256 + tid;
        if (e < N_EDGES_C) {
            atomicAdd(&deg[dst[e]], 1);
            float a1 = 0.f, a2 = 0.f;
#pragma unroll
            for (int k = 0; k < EDGE_DIM_C; ++k) {
                float ea = eattr[e * EDGE_DIM_C + k];
                a1 += ea * v[k];
                a2 += ea * v[8 + k];
            }
            ae1[e] = a1;
            ae2[e] = a2;
        }
        return;
    }

    // ---- GEMM1: H[64,256] = bf16(X[64,64]) @ Wt^T + fused dots ----
    int w = tid >> 6, l = tid & 63;
    int lr = l & 15, lg = l >> 4;
    long mbase = (long)blockIdx.x * 64;

    float asv[4], adv[4];
#pragma unroll
    for (int ni = 0; ni < 4; ++ni) {
        int col = w * 64 + ni * 16 + lr;
        asv[ni] = att_s[col];
        adv[ni] = att_d[col];
    }

    f32x4 acc[4][4];
#pragma unroll
    for (int mi = 0; mi < 4; ++mi)
#pragma unroll
        for (int ni = 0; ni < 4; ++ni) acc[mi][ni] = (f32x4){0.f, 0.f, 0.f, 0.f};

    {
        // stage A: 64 rows x 64 k (f32 -> bf16)
#pragma unroll
        for (int p = 0; p < 2; ++p) {
            int r = p * 32 + (tid >> 3);
            int c8 = tid & 7;
            long row = mbase + r;
            short8 val = {0, 0, 0, 0, 0, 0, 0, 0};
            if (row < N_NODES_C) {
                const f32x4* p4 = (const f32x4*)&X[row * IN_DIM_C + c8 * 8];
                f32x4 a0 = p4[0], a1 = p4[1];
#pragma unroll
                for (int q = 0; q < 4; ++q) val[q] = (short)f2b(a0[q]);
#pragma unroll
                for (int q = 0; q < 4; ++q) val[4 + q] = (short)f2b(a1[q]);
            }
            *(short8*)&As[r * 64 + ((c8 ^ (r & 7)) * 8)] = val;
        }
        int n = tid;
#pragma unroll
        for (int c8 = 0; c8 < 8; ++c8) {
            *(short8*)&Bs[n * 64 + ((c8 ^ (n & 7)) * 8)] =
                *(const short8*)&Wt[(long)n * IN_DIM_C + c8 * 8];
        }
        __syncthreads();
#pragma unroll
        for (int kk = 0; kk < 2; ++kk) {
            int cblk = kk * 4 + lg;
            short8 a[4], b[4];
#pragma unroll
            for (int mi = 0; mi < 4; ++mi) {
                int R = mi * 16 + lr;
                a[mi] = *(const short8*)&As[R * 64 + ((cblk ^ (R & 7)) * 8)];
            }
#pragma unroll
            for (int ni = 0; ni < 4; ++ni) {
                int Nr = w * 64 + ni * 16 + lr;
                b[ni] = *(const short8*)&Bs[Nr * 64 + ((cblk ^ (Nr & 7)) * 8)];
            }
#pragma unroll
            for (int mi = 0; mi < 4; ++mi)
#pragma unroll
                for (int ni = 0; ni < 4; ++ni)
                    acc[mi][ni] = __builtin_amdgcn_mfma_f32_16x16x32_bf16(a[mi], b[ni],
                                                                          acc[mi][ni], 0, 0, 0);
        }
        __syncthreads();
    }

#pragma unroll
    for (int mi = 0; mi < 4; ++mi) {
#pragma unroll
        for (int r = 0; r < 4; ++r) {
            int rowl = mi * 16 + lg * 4 + r;
            long row = mbase + rowl;
            float ps = 0.f, pd = 0.f;
#pragma unroll
            for (int ni = 0; ni < 4; ++ni) {
                float h = acc[mi][ni][r];
                ps += h * asv[ni];
                pd += h * adv[ni];
            }
#pragma unroll
            for (int o = 1; o < 16; o <<= 1) {
                ps += __shfl_xor(ps, o, 16);
                pd += __shfl_xor(pd, o, 16);
            }
            if (lr == 0) {
                ds[w][rowl] = ps;
                dd[w][rowl] = pd;
            }
            if (row < N_NODES_C) {
#pragma unroll
                for (int ni = 0; ni < 4; ++ni) {
                    H[row * HID_C + w * 64 + ni * 16 + lr] = f2b(acc[mi][ni][r]);
                }
            }
        }
    }
    __syncthreads();
    if (tid < 64) {
        long row = mbase + tid;
        if (row < N_NODES_C) {
            asrc[row] = ds[0][tid] + ds[1][tid] + ds[2][tid] + ds[3][tid];
            adst[row] = dd[0][tid] + dd[1][tid] + dd[2][tid] + dd[3][tid];
        }
    }
}

// ---------------- two-level scan ----------------
__global__ void k_scan1(const int* __restrict__ deg, int* __restrict__ offs,
                        int* __restrict__ bsum) {
    __shared__ int tmp[256];
    int b = blockIdx.x, tid = threadIdx.x;
    int i = b * 256 + tid;
    int v = (i < N_NODES_C) ? deg[i] : 0;
    tmp[tid] = v;
    __syncthreads();
    for (int d = 1; d < 256; d <<= 1) {
        int t = (tid >= d) ? tmp[tid - d] : 0;
        __syncthreads();
        tmp[tid] += t;
        __syncthreads();
    }
    if (i < N_NODES_C) offs[i] = tmp[tid] - v;
    if (tid == 255) bsum[b] = tmp[255];
}
__global__ void k_scan2(const int* __restrict__ bsum, int* __restrict__ boff, int nb) {
    __shared__ int tmp[256];
    int tid = threadIdx.x;
    int v = (tid < nb) ? bsum[tid] : 0;
    tmp[tid] = v;
    __syncthreads();
    for (int d = 1; d < 256; d <<= 1) {
        int t = (tid >= d) ? tmp[tid - d] : 0;
        __syncthreads();
        tmp[tid] += t;
        __syncthreads();
    }
    if (tid < nb) boff[tid] = tmp[tid] - v;
}
__global__ void k_scan3(int* __restrict__ offs, const int* __restrict__ boff,
                        int* __restrict__ cur) {
    int b = blockIdx.x, tid = threadIdx.x;
    int i = b * 256 + tid;
    if (i < N_NODES_C) {
        int o = offs[i] + boff[b];
        offs[i] = o;
        cur[i] = o;
    }
    if (i == 0) offs[N_NODES_C] = N_EDGES_C;
}

// ---------------- perm build ----------------
__global__ void k_perm(const int* __restrict__ dst, int* __restrict__ cur,
                       int* __restrict__ perm) {
    int e = blockIdx.x * blockDim.x + threadIdx.x;
    if (e >= N_EDGES_C) return;
    int pos = atomicAdd(&cur[dst[e]], 1);
    perm[pos] = e;
}

// ---------------- CSR materialization ----------------
__global__ void k_gather(const int* __restrict__ perm, const int* __restrict__ src,
                         const float* __restrict__ ae1, const float* __restrict__ ae2,
                         int* __restrict__ ssrc, float* __restrict__ sae1,
                         float* __restrict__ sae2) {
    int p = blockIdx.x * blockDim.x + threadIdx.x;
    if (p >= N_EDGES_C) return;
    int e = perm[p];
    ssrc[p] = src[e];
    sae1[p] = ae1[e];
    sae2[p] = ae2[e];
}

// ---------------- fused: aggr1(+b1,relu) -> LDS A-tile -> GEMM2 -> H2 + dots2 --------
__global__ __launch_bounds__(256) void k_aggr_gemm(
    const int* __restrict__ offs, const int* __restrict__ ssrc,
    const float* __restrict__ sae, const float* __restrict__ asrc,
    const float* __restrict__ adst, const unsigned short* __restrict__ H,
    const float* __restrict__ bias, const unsigned short* __restrict__ Wt,
    unsigned short* __restrict__ H2, const float* __restrict__ att_s,
    const float* __restrict__ att_d, float* __restrict__ asrc2,
    float* __restrict__ adst2) {
    __shared__ unsigned short As[64 * 256];  // 32 KB: g-tile [row][k], swizzled per 64-chunk
    __shared__ unsigned short Bs[256 * 64];  // 32 KB
    __shared__ float ds[4][64];
    __shared__ float dd[4][64];
    int tid = threadIdx.x;
    long mbase = (long)blockIdx.x * 64;

    // ---- phase 1: aggregate 64 nodes (8 passes x 8 halfwaves), write A-tile ----
    int hw = tid >> 5, l = tid & 31;
    int c8 = l * 8;
    for (int p = 0; p < 8; ++p) {
        int rowl = p * 8 + hw;
        long node = mbase + rowl;
        short8 rowv = {0, 0, 0, 0, 0, 0, 0, 0};
        if (node < N_NODES_C) {
            int off0 = offs[node];
            int deg = offs[node + 1] - off0;
            float adi = adst[node];
            float acc[8];
            float inv = aggr_node(off0, deg, adi, ssrc, sae, asrc, H, l, acc);
            const f32x4* b4 = (const f32x4*)&bias[c8];
            f32x4 bv0 = b4[0], bv1 = b4[1];
#pragma unroll
            for (int q = 0; q < 4; ++q)
                rowv[q] = (short)f2b(fmaxf(acc[q] * inv + bv0[q], 0.f));
#pragma unroll
            for (int q = 0; q < 4; ++q)
                rowv[4 + q] = (short)f2b(fmaxf(acc[4 + q] * inv + bv1[q], 0.f));
        }
        // element k = l*8 -> chunk = l>>3 (k0/64), c8-in-chunk = l&7
        *(short8*)&As[rowl * 256 + (l >> 3) * 64 + (((l & 7) ^ (rowl & 7)) * 8)] = rowv;
    }
    __syncthreads();

    // ---- phase 2: GEMM K=256 over the LDS A-tile ----
    int w = tid >> 6, l64 = tid & 63;
    int lr = l64 & 15, lg = l64 >> 4;

    float asv[4], adv[4];
#pragma unroll
    for (int ni = 0; ni < 4; ++ni) {
        int col = w * 64 + ni * 16 + lr;
        asv[ni] = att_s[col];
        adv[ni] = att_d[col];
    }

    f32x4 acc[4][4];
#pragma unroll
    for (int mi = 0; mi < 4; ++mi)
#pragma unroll
        for (int ni = 0; ni < 4; ++ni) acc[mi][ni] = (f32x4){0.f, 0.f, 0.f, 0.f};

    for (int k0 = 0; k0 < HID_C; k0 += 64) {
        int n = tid;
#pragma unroll
        for (int cb = 0; cb < 8; ++cb) {
            *(short8*)&Bs[n * 64 + ((cb ^ (n & 7)) * 8)] =
                *(const short8*)&Wt[(long)n * HID_C + k0 + cb * 8];
        }
        __syncthreads();
#pragma unroll
        for (int kk = 0; kk < 2; ++kk) {
            int cblk = kk * 4 + lg;
            short8 a[4], b[4];
#pragma unroll
            for (int mi = 0; mi < 4; ++mi) {
                int R = mi * 16 + lr;
                a[mi] = *(const short8*)&As[R * 256 + k0 + ((cblk ^ (R & 7)) * 8)];
            }
#pragma unroll
            for (int ni = 0; ni < 4; ++ni) {
                int Nr = w * 64 + ni * 16 + lr;
                b[ni] = *(const short8*)&Bs[Nr * 64 + ((cblk ^ (Nr & 7)) * 8)];
            }
#pragma unroll
            for (int mi = 0; mi < 4; ++mi)
#pragma unroll
                for (int ni = 0; ni < 4; ++ni)
                    acc[mi][ni] = __builtin_amdgcn_mfma_f32_16x16x32_bf16(a[mi], b[ni],
                                                                          acc[mi][ni], 0, 0, 0);
        }
        __syncthreads();
    }

#pragma unroll
    for (int mi = 0; mi < 4; ++mi) {
#pragma unroll
        for (int r = 0; r < 4; ++r) {
            int rowl = mi * 16 + lg * 4 + r;
            long row = mbase + rowl;
            float ps = 0.f, pd = 0.f;
#pragma unroll
            for (int ni = 0; ni < 4; ++ni) {
                float h = acc[mi][ni][r];
                ps += h * asv[ni];
                pd += h * adv[ni];
            }
#pragma unroll
            for (int o = 1; o < 16; o <<= 1) {
                ps += __shfl_xor(ps, o, 16);
                pd += __shfl_xor(pd, o, 16);
            }
            if (lr == 0) {
                ds[w][rowl] = ps;
                dd[w][rowl] = pd;
            }
            if (row < N_NODES_C) {
#pragma unroll
                for (int ni = 0; ni < 4; ++ni) {
                    H2[row * HID_C + w * 64 + ni * 16 + lr] = f2b(acc[mi][ni][r]);
                }
            }
        }
    }
    __syncthreads();
    if (tid < 64) {
        long row = mbase + tid;
        if (row < N_NODES_C) {
            asrc2[row] = ds[0][tid] + ds[1][tid] + ds[2][tid] + ds[3][tid];
            adst2[row] = dd[0][tid] + dd[1][tid] + dd[2][tid] + dd[3][tid];
        }
    }
}

// ---------------- final aggregation (layer 2): halfwave per node, f32 out ------------
__global__ __launch_bounds__(256) void k_aggr2(const int* __restrict__ offs,
                                               const int* __restrict__ ssrc,
                                               const float* __restrict__ sae,
                                               const float* __restrict__ asrc,
                                               const float* __restrict__ adst,
                                               const unsigned short* __restrict__ H,
                                               const float* __restrict__ bias,
                                               float* __restrict__ out) {
    int tid = threadIdx.x;
    int hw = tid >> 5;
    int l = tid & 31;
    int node = blockIdx.x * 8 + hw;
    int off0 = offs[node];
    int deg = offs[node + 1] - off0;
    float adi = adst[node];
    float acc[8];
    float inv = aggr_node(off0, deg, adi, ssrc, sae, asrc, H, l, acc);
    int c8 = l * 8;
    const f32x4* b4 = (const f32x4*)&bias[c8];
    f32x4 bv0 = b4[0], bv1 = b4[1];
    f32x4 r0, r1;
#pragma unroll
    for (int q = 0; q < 4; ++q) r0[q] = acc[q] * inv + bv0[q];
#pragma unroll
    for (int q = 0; q < 4; ++q) r1[q] = acc[4 + q] * inv + bv1[q];
    *(f32x4*)&out[(long)node * HID_C + c8] = r0;
    *(f32x4*)&out[(long)node * HID_C + c8 + 4] = r1;
}

extern "C" void kernel_launch(void* const* d_in, const int* in_sizes, int n_in,
                              void* d_out, int out_size, void* d_ws, size_t ws_size,
                              hipStream_t stream) {
    const float* x     = (const float*)d_in[0];
    const int*   ei    = (const int*)d_in[1];     // [2, E]: row0=src, row1=dst
    const float* eattr = (const float*)d_in[2];
    const float* W1    = (const float*)d_in[3];
    const float* atts1 = (const float*)d_in[4];
    const float* attd1 = (const float*)d_in[5];
    const float* We1   = (const float*)d_in[6];
    const float* atte1 = (const float*)d_in[7];
    const float* b1    = (const float*)d_in[8];
    const float* W2    = (const float*)d_in[9];
    const float* atts2 = (const float*)d_in[10];
    const float* attd2 = (const float*)d_in[11];
    const float* We2   = (const float*)d_in[12];
    const float* atte2 = (const float*)d_in[13];
    const float* b2    = (const float*)d_in[14];
    float* out = (float*)d_out;

    char* ws = (char*)d_ws;
    size_t off = 0;
    auto alloc = [&](size_t bytes) -> void* {
        void* p = ws + off;
        off = (off + bytes + 255) & ~(size_t)255;
        return p;
    };
    int*   deg   = (int*)alloc((size_t)N_NODES_C * 4);
    int*   offs  = (int*)alloc(((size_t)N_NODES_C + 1) * 4);
    int*   cur   = (int*)alloc((size_t)N_NODES_C * 4);
    int*   perm  = (int*)alloc((size_t)N_EDGES_C * 4);
    int*   ssrc  = (int*)alloc((size_t)N_EDGES_C * 4);
    float* ae1   = (float*)alloc((size_t)N_EDGES_C * 4);
    float* ae2   = (float*)alloc((size_t)N_EDGES_C * 4);
    float* sae1  = (float*)alloc((size_t)N_EDGES_C * 4);
    float* sae2  = (float*)alloc((size_t)N_EDGES_C * 4);
    float* asrc  = (float*)alloc((size_t)N_NODES_C * 4);
    float* adst  = (float*)alloc((size_t)N_NODES_C * 4);
    float* asrc2 = (float*)alloc((size_t)N_NODES_C * 4);
    float* adst2 = (float*)alloc((size_t)N_NODES_C * 4);
    float* v     = (float*)alloc(64);
    int*   bsum  = (int*)alloc(256 * 4);
    int*   boff  = (int*)alloc(257 * 4);
    unsigned short* W1t = (unsigned short*)alloc((size_t)HID_C * IN_DIM_C * 2);
    unsigned short* W2t = (unsigned short*)alloc((size_t)HID_C * HID_C * 2);
    unsigned short* h1  = (unsigned short*)alloc((size_t)N_NODES_C * HID_C * 2);
    unsigned short* h2  = (unsigned short*)alloc((size_t)N_NODES_C * HID_C * 2);

    const int* src = ei;
    const int* dst = ei + N_EDGES_C;
    int nb = (N_NODES_C + 255) / 256;  // 196
    int pre_blocks = (N_EDGES_C + 255) / 256;  // 3125
    int gemm_grid = (N_NODES_C + 63) / 64;     // 782 == GEMM1_BLOCKS

    k_prep<<<256, 256, 0, stream>>>(W1, W2, W1t, W2t, We1, atte1, We2, atte2, v, deg);
    k_pre_gemm1<<<GEMM1_BLOCKS + pre_blocks, 256, 0, stream>>>(
        x, W1t, h1, atts1, attd1, asrc, adst, dst, eattr, v, deg, ae1, ae2);
    k_scan1<<<nb, 256, 0, stream>>>(deg, offs, bsum);
    k_scan2<<<1, 256, 0, stream>>>(bsum, boff, nb);
    k_scan3<<<nb, 256, 0, stream>>>(offs, boff, cur);
    k_perm<<<pre_blocks, 256, 0, stream>>>(dst, cur, perm);
    k_gather<<<pre_blocks, 256, 0, stream>>>(perm, src, ae1, ae2, ssrc, sae1, sae2);

    k_aggr_gemm<<<gemm_grid, 256, 0, stream>>>(offs, ssrc, sae1, asrc, adst, h1, b1,
                                               W2t, h2, atts2, attd2, asrc2, adst2);
    k_aggr2<<<N_NODES_C / 8, 256, 0, stream>>>(offs, ssrc, sae2, asrc2, adst2, h2, b2, out);
}

// Round 10
// 297.733 us; speedup vs baseline: 1.6944x; 1.0148x over previous
//
#include <hip/hip_runtime.h>
#include <hip/hip_bf16.h>

#define N_NODES_C 50000
#define N_EDGES_C 800000
#define IN_DIM_C 64
#define HID_C 256
#define EDGE_DIM_C 6
#define NEG_SLOPE_C 0.2f

typedef short short8 __attribute__((ext_vector_type(8)));
typedef float f32x4 __attribute__((ext_vector_type(4)));

static __device__ __forceinline__ float b2f(unsigned short u) {
    union { unsigned int i; float f; } x;
    x.i = ((unsigned int)u) << 16;
    return x.f;
}
static __device__ __forceinline__ unsigned short f2b(float f) {
    union { __hip_bfloat16 h; unsigned short u; } x;
    x.h = __float2bfloat16(f);
    return x.u;
}

// ---- shared aggregation core: one halfwave aggregates one node's 8 columns/lane ----
static __device__ __forceinline__ float aggr_node(int off0, int deg, float adi,
                                                  const int* __restrict__ ssrc,
                                                  const float* __restrict__ sae,
                                                  const float* __restrict__ asrc,
                                                  const unsigned short* __restrict__ H,
                                                  int l, float* acc) {
    int sidx0 = 0, sidx1 = 0;
    float w0 = 0.f, w1 = 0.f;
    if (l < deg) {
        sidx0 = ssrc[off0 + l];
        float a = asrc[sidx0] + adi + sae[off0 + l];
        a = (a > 0.f) ? a : NEG_SLOPE_C * a;
        w0 = __expf(a);
    }
    if (32 + l < deg) {
        sidx1 = ssrc[off0 + 32 + l];
        float a = asrc[sidx1] + adi + sae[off0 + 32 + l];
        a = (a > 0.f) ? a : NEG_SLOPE_C * a;
        w1 = __expf(a);
    }
    float s = w0 + w1;
    for (int j = 64 + l; j < deg; j += 32) {  // cold tail
        int si = ssrc[off0 + j];
        float a = asrc[si] + adi + sae[off0 + j];
        a = (a > 0.f) ? a : NEG_SLOPE_C * a;
        s += __expf(a);
    }
#pragma unroll
    for (int o = 16; o > 0; o >>= 1) s += __shfl_xor(s, o, 32);
    float inv = 1.0f / (s + 1e-16f);

    int c8 = l * 8;
#pragma unroll
    for (int q = 0; q < 8; ++q) acc[q] = 0.f;

    auto fetch = [&](int j, int& si, float& wv) {
        if (j < 32) {
            si = __shfl(sidx0, j, 32);
            wv = __shfl(w0, j, 32);
        } else if (j < 64) {
            si = __shfl(sidx1, j - 32, 32);
            wv = __shfl(w1, j - 32, 32);
        } else {
            si = ssrc[off0 + j];
            float a = asrc[si] + adi + sae[off0 + j];
            a = (a > 0.f) ? a : NEG_SLOPE_C * a;
            wv = __expf(a);
        }
    };

    int j = 0;
    for (; j + 7 < deg; j += 8) {
        int ii[8];
        float uu[8];
#pragma unroll
        for (int q = 0; q < 8; ++q) fetch(j + q, ii[q], uu[q]);
        short8 h[8];
#pragma unroll
        for (int q = 0; q < 8; ++q) h[q] = *(const short8*)&H[(long)ii[q] * HID_C + c8];
#pragma unroll
        for (int t = 0; t < 8; ++t)
#pragma unroll
            for (int q = 0; q < 8; ++q) acc[q] += uu[t] * b2f((unsigned short)h[t][q]);
    }
    for (; j + 3 < deg; j += 4) {
        int ii[4];
        float uu[4];
#pragma unroll
        for (int q = 0; q < 4; ++q) fetch(j + q, ii[q], uu[q]);
        short8 h[4];
#pragma unroll
        for (int q = 0; q < 4; ++q) h[q] = *(const short8*)&H[(long)ii[q] * HID_C + c8];
#pragma unroll
        for (int t = 0; t < 4; ++t)
#pragma unroll
            for (int q = 0; q < 8; ++q) acc[q] += uu[t] * b2f((unsigned short)h[t][q]);
    }
    for (; j < deg; ++j) {
        int i0;
        float u0;
        fetch(j, i0, u0);
        short8 h0 = *(const short8*)&H[(long)i0 * HID_C + c8];
#pragma unroll
        for (int q = 0; q < 8; ++q) acc[q] += u0 * b2f((unsigned short)h0[q]);
    }
    return inv;
}

// ---------------- prep: W transposes + v12 (block 255) + zero deg ----------------
__global__ void k_prep(const float* __restrict__ W1, const float* __restrict__ W2,
                       unsigned short* __restrict__ W1t, unsigned short* __restrict__ W2t,
                       const float* __restrict__ We1, const float* __restrict__ atte1,
                       const float* __restrict__ We2, const float* __restrict__ atte2,
                       float* __restrict__ v, int* __restrict__ deg) {
    int tid = threadIdx.x;
    int i = blockIdx.x * blockDim.x + tid;
    if (i < N_NODES_C) deg[i] = 0;
    if (i < IN_DIM_C * HID_C) {
        int k = i >> 8, n = i & 255;
        W1t[n * IN_DIM_C + k] = f2b(W1[i]);
    }
    if (i < HID_C * HID_C) {
        int k = i >> 8, n = i & 255;
        W2t[n * HID_C + k] = f2b(W2[i]);
    }
    if (blockIdx.x == 255) {
        __shared__ float red[256];
        for (int layer = 0; layer < 2; ++layer) {
            const float* We = layer ? We2 : We1;
            const float* ae = layer ? atte2 : atte1;
            for (int k = 0; k < EDGE_DIM_C; ++k) {
                red[tid] = We[k * HID_C + tid] * ae[tid];
                __syncthreads();
                for (int s = 128; s > 0; s >>= 1) {
                    if (tid < s) red[tid] += red[tid + s];
                    __syncthreads();
                }
                if (tid == 0) v[layer * 8 + k] = red[0];
                __syncthreads();
            }
        }
    }
}

#define GEMM1_BLOCKS 782  // ceil(50000/64)

// ---------------- fused: GEMM1 (blocks < 782) + edge-pre (blocks >= 782) ----------
__global__ __launch_bounds__(256) void k_pre_gemm1(
    const float* __restrict__ X, const unsigned short* __restrict__ Wt,
    unsigned short* __restrict__ H, const float* __restrict__ att_s,
    const float* __restrict__ att_d, float* __restrict__ asrc,
    float* __restrict__ adst,
    const int* __restrict__ dst, const float* __restrict__ eattr,
    const float* __restrict__ v, int* __restrict__ deg,
    float* __restrict__ ae1, float* __restrict__ ae2) {
    __shared__ unsigned short As[64 * 64];
    __shared__ unsigned short Bs[256 * 64];
    __shared__ float ds[4][64];
    __shared__ float dd[4][64];
    int tid = threadIdx.x;

    if (blockIdx.x >= GEMM1_BLOCKS) {
        int e = (blockIdx.x - GEMM1_BLOCKS) * 256 + tid;
        if (e < N_EDGES_C) {
            atomicAdd(&deg[dst[e]], 1);
            float a1 = 0.f, a2 = 0.f;
#pragma unroll
            for (int k = 0; k < EDGE_DIM_C; ++k) {
                float ea = eattr[e * EDGE_DIM_C + k];
                a1 += ea * v[k];
                a2 += ea * v[8 + k];
            }
            ae1[e] = a1;
            ae2[e] = a2;
        }
        return;
    }

    int w = tid >> 6, l = tid & 63;
    int lr = l & 15, lg = l >> 4;
    long mbase = (long)blockIdx.x * 64;

    float asv[4], adv[4];
#pragma unroll
    for (int ni = 0; ni < 4; ++ni) {
        int col = w * 64 + ni * 16 + lr;
        asv[ni] = att_s[col];
        adv[ni] = att_d[col];
    }

    f32x4 acc[4][4];
#pragma unroll
    for (int mi = 0; mi < 4; ++mi)
#pragma unroll
        for (int ni = 0; ni < 4; ++ni) acc[mi][ni] = (f32x4){0.f, 0.f, 0.f, 0.f};

    {
#pragma unroll
        for (int p = 0; p < 2; ++p) {
            int r = p * 32 + (tid >> 3);
            int c8 = tid & 7;
            long row = mbase + r;
            short8 val = {0, 0, 0, 0, 0, 0, 0, 0};
            if (row < N_NODES_C) {
                const f32x4* p4 = (const f32x4*)&X[row * IN_DIM_C + c8 * 8];
                f32x4 a0 = p4[0], a1 = p4[1];
#pragma unroll
                for (int q = 0; q < 4; ++q) val[q] = (short)f2b(a0[q]);
#pragma unroll
                for (int q = 0; q < 4; ++q) val[4 + q] = (short)f2b(a1[q]);
            }
            *(short8*)&As[r * 64 + ((c8 ^ (r & 7)) * 8)] = val;
        }
        int n = tid;
#pragma unroll
        for (int c8 = 0; c8 < 8; ++c8) {
            *(short8*)&Bs[n * 64 + ((c8 ^ (n & 7)) * 8)] =
                *(const short8*)&Wt[(long)n * IN_DIM_C + c8 * 8];
        }
        __syncthreads();
#pragma unroll
        for (int kk = 0; kk < 2; ++kk) {
            int cblk = kk * 4 + lg;
            short8 a[4], b[4];
#pragma unroll
            for (int mi = 0; mi < 4; ++mi) {
                int R = mi * 16 + lr;
                a[mi] = *(const short8*)&As[R * 64 + ((cblk ^ (R & 7)) * 8)];
            }
#pragma unroll
            for (int ni = 0; ni < 4; ++ni) {
                int Nr = w * 64 + ni * 16 + lr;
                b[ni] = *(const short8*)&Bs[Nr * 64 + ((cblk ^ (Nr & 7)) * 8)];
            }
#pragma unroll
            for (int mi = 0; mi < 4; ++mi)
#pragma unroll
                for (int ni = 0; ni < 4; ++ni)
                    acc[mi][ni] = __builtin_amdgcn_mfma_f32_16x16x32_bf16(a[mi], b[ni],
                                                                          acc[mi][ni], 0, 0, 0);
        }
        __syncthreads();
    }

#pragma unroll
    for (int mi = 0; mi < 4; ++mi) {
#pragma unroll
        for (int r = 0; r < 4; ++r) {
            int rowl = mi * 16 + lg * 4 + r;
            long row = mbase + rowl;
            float ps = 0.f, pd = 0.f;
#pragma unroll
            for (int ni = 0; ni < 4; ++ni) {
                float h = acc[mi][ni][r];
                ps += h * asv[ni];
                pd += h * adv[ni];
            }
#pragma unroll
            for (int o = 1; o < 16; o <<= 1) {
                ps += __shfl_xor(ps, o, 16);
                pd += __shfl_xor(pd, o, 16);
            }
            if (lr == 0) {
                ds[w][rowl] = ps;
                dd[w][rowl] = pd;
            }
            if (row < N_NODES_C) {
#pragma unroll
                for (int ni = 0; ni < 4; ++ni) {
                    H[row * HID_C + w * 64 + ni * 16 + lr] = f2b(acc[mi][ni][r]);
                }
            }
        }
    }
    __syncthreads();
    if (tid < 64) {
        long row = mbase + tid;
        if (row < N_NODES_C) {
            asrc[row] = ds[0][tid] + ds[1][tid] + ds[2][tid] + ds[3][tid];
            adst[row] = dd[0][tid] + dd[1][tid] + dd[2][tid] + dd[3][tid];
        }
    }
}

// ---------------- two-level scan ----------------
__global__ void k_scan1(const int* __restrict__ deg, int* __restrict__ offs,
                        int* __restrict__ bsum) {
    __shared__ int tmp[256];
    int b = blockIdx.x, tid = threadIdx.x;
    int i = b * 256 + tid;
    int v = (i < N_NODES_C) ? deg[i] : 0;
    tmp[tid] = v;
    __syncthreads();
    for (int d = 1; d < 256; d <<= 1) {
        int t = (tid >= d) ? tmp[tid - d] : 0;
        __syncthreads();
        tmp[tid] += t;
        __syncthreads();
    }
    if (i < N_NODES_C) offs[i] = tmp[tid] - v;
    if (tid == 255) bsum[b] = tmp[255];
}
__global__ void k_scan2(const int* __restrict__ bsum, int* __restrict__ boff, int nb) {
    __shared__ int tmp[256];
    int tid = threadIdx.x;
    int v = (tid < nb) ? bsum[tid] : 0;
    tmp[tid] = v;
    __syncthreads();
    for (int d = 1; d < 256; d <<= 1) {
        int t = (tid >= d) ? tmp[tid - d] : 0;
        __syncthreads();
        tmp[tid] += t;
        __syncthreads();
    }
    if (tid < nb) boff[tid] = tmp[tid] - v;
}
__global__ void k_scan3(int* __restrict__ offs, const int* __restrict__ boff,
                        int* __restrict__ cur) {
    int b = blockIdx.x, tid = threadIdx.x;
    int i = b * 256 + tid;
    if (i < N_NODES_C) {
        int o = offs[i] + boff[b];
        offs[i] = o;
        cur[i] = o;
    }
    if (i == 0) offs[N_NODES_C] = N_EDGES_C;
}

// ---------------- perm build ----------------
__global__ void k_perm(const int* __restrict__ dst, int* __restrict__ cur,
                       int* __restrict__ perm) {
    int e = blockIdx.x * blockDim.x + threadIdx.x;
    if (e >= N_EDGES_C) return;
    int pos = atomicAdd(&cur[dst[e]], 1);
    perm[pos] = e;
}

// ---------------- CSR materialization ----------------
__global__ void k_gather(const int* __restrict__ perm, const int* __restrict__ src,
                         const float* __restrict__ ae1, const float* __restrict__ ae2,
                         int* __restrict__ ssrc, float* __restrict__ sae1,
                         float* __restrict__ sae2) {
    int p = blockIdx.x * blockDim.x + threadIdx.x;
    if (p >= N_EDGES_C) return;
    int e = perm[p];
    ssrc[p] = src[e];
    sae1[p] = ae1[e];
    sae2[p] = ae2[e];
}

// ---------------- fused: aggr1(+b1,relu) -> LDS A-tile -> GEMM2 (B direct from L2) ----
// LDS = 34 KB -> 4 blocks/CU; GEMM phase barrier-free after the single As barrier.
__global__ __launch_bounds__(256) void k_aggr_gemm(
    const int* __restrict__ offs, const int* __restrict__ ssrc,
    const float* __restrict__ sae, const float* __restrict__ asrc,
    const float* __restrict__ adst, const unsigned short* __restrict__ H,
    const float* __restrict__ bias, const unsigned short* __restrict__ Wt,
    unsigned short* __restrict__ H2, const float* __restrict__ att_s,
    const float* __restrict__ att_d, float* __restrict__ asrc2,
    float* __restrict__ adst2) {
    __shared__ unsigned short As[64 * 256];  // 32 KB, swizzled per 64-elem chunk
    __shared__ float ds[4][64];
    __shared__ float dd[4][64];
    int tid = threadIdx.x;
    long mbase = (long)blockIdx.x * 64;

    // ---- phase 1: aggregate 64 nodes (8 passes x 8 halfwaves), write A-tile ----
    int hw = tid >> 5, l = tid & 31;
    int c8 = l * 8;
    for (int p = 0; p < 8; ++p) {
        int rowl = p * 8 + hw;
        long node = mbase + rowl;
        short8 rowv = {0, 0, 0, 0, 0, 0, 0, 0};
        if (node < N_NODES_C) {
            int off0 = offs[node];
            int deg = offs[node + 1] - off0;
            float adi = adst[node];
            float acc[8];
            float inv = aggr_node(off0, deg, adi, ssrc, sae, asrc, H, l, acc);
            const f32x4* b4 = (const f32x4*)&bias[c8];
            f32x4 bv0 = b4[0], bv1 = b4[1];
#pragma unroll
            for (int q = 0; q < 4; ++q)
                rowv[q] = (short)f2b(fmaxf(acc[q] * inv + bv0[q], 0.f));
#pragma unroll
            for (int q = 0; q < 4; ++q)
                rowv[4 + q] = (short)f2b(fmaxf(acc[4 + q] * inv + bv1[q], 0.f));
        }
        *(short8*)&As[rowl * 256 + (l >> 3) * 64 + (((l & 7) ^ (rowl & 7)) * 8)] = rowv;
    }
    __syncthreads();

    // ---- phase 2: GEMM K=256, B fragments straight from W2t (L2-resident) ----
    int w = tid >> 6, l64 = tid & 63;
    int lr = l64 & 15, lg = l64 >> 4;

    float asv[4], adv[4];
#pragma unroll
    for (int ni = 0; ni < 4; ++ni) {
        int col = w * 64 + ni * 16 + lr;
        asv[ni] = att_s[col];
        adv[ni] = att_d[col];
    }

    f32x4 acc[4][4];
#pragma unroll
    for (int mi = 0; mi < 4; ++mi)
#pragma unroll
        for (int ni = 0; ni < 4; ++ni) acc[mi][ni] = (f32x4){0.f, 0.f, 0.f, 0.f};

#pragma unroll
    for (int k0 = 0; k0 < HID_C; k0 += 64) {
#pragma unroll
        for (int kk = 0; kk < 2; ++kk) {
            int cblk = kk * 4 + lg;
            short8 a[4], b[4];
#pragma unroll
            for (int mi = 0; mi < 4; ++mi) {
                int R = mi * 16 + lr;
                a[mi] = *(const short8*)&As[R * 256 + k0 + ((cblk ^ (R & 7)) * 8)];
            }
#pragma unroll
            for (int ni = 0; ni < 4; ++ni) {
                int Nr = w * 64 + ni * 16 + lr;
                b[ni] = *(const short8*)&Wt[(long)Nr * HID_C + k0 + cblk * 8];
            }
#pragma unroll
            for (int mi = 0; mi < 4; ++mi)
#pragma unroll
                for (int ni = 0; ni < 4; ++ni)
                    acc[mi][ni] = __builtin_amdgcn_mfma_f32_16x16x32_bf16(a[mi], b[ni],
                                                                          acc[mi][ni], 0, 0, 0);
        }
    }

#pragma unroll
    for (int mi = 0; mi < 4; ++mi) {
#pragma unroll
        for (int r = 0; r < 4; ++r) {
            int rowl = mi * 16 + lg * 4 + r;
            long row = mbase + rowl;
            float ps = 0.f, pd = 0.f;
#pragma unroll
            for (int ni = 0; ni < 4; ++ni) {
                float h = acc[mi][ni][r];
                ps += h * asv[ni];
                pd += h * adv[ni];
            }
#pragma unroll
            for (int o = 1; o < 16; o <<= 1) {
                ps += __shfl_xor(ps, o, 16);
                pd += __shfl_xor(pd, o, 16);
            }
            if (lr == 0) {
                ds[w][rowl] = ps;
                dd[w][rowl] = pd;
            }
            if (row < N_NODES_C) {
#pragma unroll
                for (int ni = 0; ni < 4; ++ni) {
                    H2[row * HID_C + w * 64 + ni * 16 + lr] = f2b(acc[mi][ni][r]);
                }
            }
        }
    }
    __syncthreads();
    if (tid < 64) {
        long row = mbase + tid;
        if (row < N_NODES_C) {
            asrc2[row] = ds[0][tid] + ds[1][tid] + ds[2][tid] + ds[3][tid];
            adst2[row] = dd[0][tid] + dd[1][tid] + dd[2][tid] + dd[3][tid];
        }
    }
}

// ---------------- final aggregation (layer 2): halfwave per node, f32 out ------------
__global__ __launch_bounds__(256) void k_aggr2(const int* __restrict__ offs,
                                               const int* __restrict__ ssrc,
                                               const float* __restrict__ sae,
                                               const float* __restrict__ asrc,
                                               const float* __restrict__ adst,
                                               const unsigned short* __restrict__ H,
                                               const float* __restrict__ bias,
                                               float* __restrict__ out) {
    int tid = threadIdx.x;
    int hw = tid >> 5;
    int l = tid & 31;
    int node = blockIdx.x * 8 + hw;
    int off0 = offs[node];
    int deg = offs[node + 1] - off0;
    float adi = adst[node];
    float acc[8];
    float inv = aggr_node(off0, deg, adi, ssrc, sae, asrc, H, l, acc);
    int c8 = l * 8;
    const f32x4* b4 = (const f32x4*)&bias[c8];
    f32x4 bv0 = b4[0], bv1 = b4[1];
    f32x4 r0, r1;
#pragma unroll
    for (int q = 0; q < 4; ++q) r0[q] = acc[q] * inv + bv0[q];
#pragma unroll
    for (int q = 0; q < 4; ++q) r1[q] = acc[4 + q] * inv + bv1[q];
    *(f32x4*)&out[(long)node * HID_C + c8] = r0;
    *(f32x4*)&out[(long)node * HID_C + c8 + 4] = r1;
}

extern "C" void kernel_launch(void* const* d_in, const int* in_sizes, int n_in,
                              void* d_out, int out_size, void* d_ws, size_t ws_size,
                              hipStream_t stream) {
    const float* x     = (const float*)d_in[0];
    const int*   ei    = (const int*)d_in[1];     // [2, E]: row0=src, row1=dst
    const float* eattr = (const float*)d_in[2];
    const float* W1    = (const float*)d_in[3];
    const float* atts1 = (const float*)d_in[4];
    const float* attd1 = (const float*)d_in[5];
    const float* We1   = (const float*)d_in[6];
    const float* atte1 = (const float*)d_in[7];
    const float* b1    = (const float*)d_in[8];
    const float* W2    = (const float*)d_in[9];
    const float* atts2 = (const float*)d_in[10];
    const float* attd2 = (const float*)d_in[11];
    const float* We2   = (const float*)d_in[12];
    const float* atte2 = (const float*)d_in[13];
    const float* b2    = (const float*)d_in[14];
    float* out = (float*)d_out;

    char* ws = (char*)d_ws;
    size_t off = 0;
    auto alloc = [&](size_t bytes) -> void* {
        void* p = ws + off;
        off = (off + bytes + 255) & ~(size_t)255;
        return p;
    };
    int*   deg   = (int*)alloc((size_t)N_NODES_C * 4);
    int*   offs  = (int*)alloc(((size_t)N_NODES_C + 1) * 4);
    int*   cur   = (int*)alloc((size_t)N_NODES_C * 4);
    int*   perm  = (int*)alloc((size_t)N_EDGES_C * 4);
    int*   ssrc  = (int*)alloc((size_t)N_EDGES_C * 4);
    float* ae1   = (float*)alloc((size_t)N_EDGES_C * 4);
    float* ae2   = (float*)alloc((size_t)N_EDGES_C * 4);
    float* sae1  = (float*)alloc((size_t)N_EDGES_C * 4);
    float* sae2  = (float*)alloc((size_t)N_EDGES_C * 4);
    float* asrc  = (float*)alloc((size_t)N_NODES_C * 4);
    float* adst  = (float*)alloc((size_t)N_NODES_C * 4);
    float* asrc2 = (float*)alloc((size_t)N_NODES_C * 4);
    float* adst2 = (float*)alloc((size_t)N_NODES_C * 4);
    float* v     = (float*)alloc(64);
    int*   bsum  = (int*)alloc(256 * 4);
    int*   boff  = (int*)alloc(257 * 4);
    unsigned short* W1t = (unsigned short*)alloc((size_t)HID_C * IN_DIM_C * 2);
    unsigned short* W2t = (unsigned short*)alloc((size_t)HID_C * HID_C * 2);
    unsigned short* h1  = (unsigned short*)alloc((size_t)N_NODES_C * HID_C * 2);
    unsigned short* h2  = (unsigned short*)alloc((size_t)N_NODES_C * HID_C * 2);

    const int* src = ei;
    const int* dst = ei + N_EDGES_C;
    int nb = (N_NODES_C + 255) / 256;  // 196
    int pre_blocks = (N_EDGES_C + 255) / 256;  // 3125
    int gemm_grid = (N_NODES_C + 63) / 64;     // 782 == GEMM1_BLOCKS

    k_prep<<<256, 256, 0, stream>>>(W1, W2, W1t, W2t, We1, atte1, We2, atte2, v, deg);
    k_pre_gemm1<<<GEMM1_BLOCKS + pre_blocks, 256, 0, stream>>>(
        x, W1t, h1, atts1, attd1, asrc, adst, dst, eattr, v, deg, ae1, ae2);
    k_scan1<<<nb, 256, 0, stream>>>(deg, offs, bsum);
    k_scan2<<<1, 256, 0, stream>>>(bsum, boff, nb);
    k_scan3<<<nb, 256, 0, stream>>>(offs, boff, cur);
    k_perm<<<pre_blocks, 256, 0, stream>>>(dst, cur, perm);
    k_gather<<<pre_blocks, 256, 0, stream>>>(perm, src, ae1, ae2, ssrc, sae1, sae2);

    k_aggr_gemm<<<gemm_grid, 256, 0, stream>>>(offs, ssrc, sae1, asrc, adst, h1, b1,
                                               W2t, h2, atts2, attd2, asrc2, adst2);
    k_aggr2<<<N_NODES_C / 8, 256, 0, stream>>>(offs, ssrc, sae2, asrc2, adst2, h2, b2, out);
}